// Round 19
// baseline (231.393 us; speedup 1.0000x reference)
//
#include <hip/hip_runtime.h>

// MoE top-2 SwiGLU (fp32 in/out, fp16 MFMA internal).
// Dispatches: memset(counts) -> prep_k (route + cvt x + transpose w13 + w2) ->
// gemm1 (256x(64g+64u), BK=32, 512thr/8wave) ->
// gemm2 (256x64, BK=64, dbuf, 512thr/8wave).
// R28/R29 gemm2 = M=256 demand reduction, composing ONLY verified pieces:
//   R22's measured loop/swizzle/epilogue (41.9us direct counters) +
//   R26's measured 512-thr/8-wave M=256 decomposition (passed, won on gemm1).
//   Blocks 1088->~312, read demand 408->~200MB (-51%), LDS 80KB -> 2 blk/CU
//   x 8 waves = 16 waves/CU (vs R22's 12). Per-wave tile stays 64x32.
//   (R28 bench lost to broker timeout; R29 = same source.)
// Machine-speed note: runs R25-R27 were on a slow node (gemm1 HBM 1510-1530
// vs 1650-1670 fast); compare residuals same-machine. R27 residual 141.9 <
// R26's 144.8 -> R22-config gemm2 >= N=128 variant; R26 gemm1 M=256 stable
// x5 (62.5-63.3 slow ~= 59-60 fast).
// Session learned (direct measurements):
//   - fillBufferAligned 41.5us @80% HBM = harness ws re-poison, untouchable.
//   - gemm1: dbuf regressed (R11), BK=64 regressed, swap epilogue regressed
//     (R19: per-lane half4 to 16 rows de-coalesces), absorption regressed
//     (R18/R21), split dispatch +21 (R22). M=256 won (R26).
//   - gemm2: dbuf won (R11); occupancy BK=32 neutral (R23); N=128 neutral
//     (R24-27 residuals); demand is the remaining lever (this round).
//   - Derived OccupancyPercent unreliable (~27-29 regardless of config).
// h_ws SORTED layout (row = rowbase[e]+m): gemm1 stores m-contiguous, gemm2
// A-streams sequentially (scatter deferred to C-write). Grid orders: gemm1
// n0-fastest, gemm2 m-fastest (R9). XOR seg swizzle keeps conflicts 0.
// Session bests: R8 201.3 / R20 196.6 (fast machine).

#define H_DIM 512
#define I_DIM 1024
#define E_NUM 8
#define P_PAIRS 16384
#define CAP P_PAIRS
#define MAX_TILES1 71    // 256-granularity: sum ceil(ne/256) <= 64+7

// prep_k block ranges
#define PREP_TW13 2048              // (2I/64=32) x (H/64=8) x E=8
#define PREP_TW2 1024               // (H/64=8) x (I/64=16) x E=8
#define PREP_CVT 2048               // 8192*512 / (256*8)
#define PREP_ROUTE 64               // 16384 / 256
#define PREP_BLOCKS (PREP_TW13 + PREP_TW2 + PREP_CVT + PREP_ROUTE)

typedef _Float16 half8 __attribute__((ext_vector_type(8)));
typedef float f32x4 __attribute__((ext_vector_type(4)));
typedef unsigned int u32;
typedef const __attribute__((address_space(1))) u32* gas_t;
typedef __attribute__((address_space(3))) u32* las_t;

__device__ __forceinline__ void glds16(const void* g, void* l) {
  __builtin_amdgcn_global_load_lds((gas_t)g, (las_t)l, 16, 0, 0);
}

// derive (e, m0, ne, rowbase) for compact tile id ty at GRAN granularity
template <int GRAN_LOG2>
__device__ __forceinline__ bool tile_decode_g(const int* counts, int ty, int& e,
                                              int& m0, int& ne, int& rb) {
  int base = 0;
  rb = 0;
  const int gm1 = (1 << GRAN_LOG2) - 1;
  for (e = 0; e < E_NUM; ++e) {
    ne = counts[e];
    const int nt = (ne + gm1) >> GRAN_LOG2;
    if (ty < base + nt) { m0 = (ty - base) << GRAN_LOG2; return true; }
    base += nt;
    rb += ne;
  }
  return false;
}

// ------------------------------------------------------------------- prep ---
__global__ __launch_bounds__(256) void prep_k(
    const float* __restrict__ x, const int* __restrict__ idx,
    const float* __restrict__ w13, const float* __restrict__ w2,
    int* __restrict__ counts, int* __restrict__ lists,
    _Float16* __restrict__ xh, _Float16* __restrict__ w13t,
    _Float16* __restrict__ w2t) {
  __shared__ __align__(16) _Float16 tile[64][72];  // 9216 B (route reuses head)
  const int b = blockIdx.x;
  const int tid = threadIdx.x;

  if (b < PREP_TW13 + PREP_TW2) {
    const float* src;
    _Float16* dst;
    int R, C, c0, r0;
    if (b < PREP_TW13) {
      R = H_DIM; C = 2 * I_DIM;
      const int e = b >> 8;
      c0 = (b & 31) * 64;
      r0 = ((b >> 5) & 7) * 64;
      src = w13 + (size_t)e * R * C;
      dst = w13t + (size_t)e * C * R;
    } else {
      const int l = b - PREP_TW13;
      R = I_DIM; C = H_DIM;
      const int e = l >> 7;
      c0 = (l & 7) * 64;
      r0 = ((l >> 3) & 15) * 64;
      src = w2 + (size_t)e * R * C;
      dst = w2t + (size_t)e * C * R;
    }
    {
      const int r = tid >> 4;
      const int c4 = (tid & 15) * 4;
      for (int pass = 0; pass < 4; ++pass) {
        f32x4 v = *(const f32x4*)(src + (size_t)(r0 + pass * 16 + r) * C + c0 + c4);
        for (int j = 0; j < 4; ++j) tile[c4 + j][pass * 16 + r] = (_Float16)v[j];
      }
    }
    __syncthreads();
    {
      const int c = tid >> 3;
      const int r8 = (tid & 7) * 8;
      for (int pass = 0; pass < 2; ++pass) {
        half8 h = *(const half8*)&tile[pass * 32 + c][r8];
        *(half8*)(dst + (size_t)(c0 + pass * 32 + c) * R + r0 + r8) = h;
      }
    }
  } else if (b < PREP_TW13 + PREP_TW2 + PREP_CVT) {
    const int l = b - (PREP_TW13 + PREP_TW2);
    const size_t i = ((size_t)l * 256 + tid) * 8;
    f32x4 v0 = *(const f32x4*)(x + i);
    f32x4 v1 = *(const f32x4*)(x + i + 4);
    half8 h;
    for (int j = 0; j < 4; ++j) { h[j] = (_Float16)v0[j]; h[j + 4] = (_Float16)v1[j]; }
    *(half8*)(xh + i) = h;
  } else {
    int* lcnt = (int*)&tile[0][0];
    int* lbase = lcnt + E_NUM;
    const int l = b - (PREP_TW13 + PREP_TW2 + PREP_CVT);
    if (tid < E_NUM) lcnt[tid] = 0;
    __syncthreads();
    const int p = l * 256 + tid;
    const int e = idx[p];
    const int r = atomicAdd(&lcnt[e], 1);
    __syncthreads();
    if (tid < E_NUM) lbase[tid] = atomicAdd(&counts[tid], lcnt[tid]);
    __syncthreads();
    lists[e * CAP + lbase[e] + r] = p;
  }
}

// ------------------------------------------------------------------ GEMM 1 ---
// R26: 256 gathered pairs x (64 gate + 64 up cols), K=512, BK=32.
// 512 threads, 8 waves (4m x 2n); per-wave tile 64x32x(g+u) = proven shape.
// Grid: x = n0 (fastest, shares random A-gather), y = m-tile (256-gran).
// Single-buffered 2-barrier loop; non-swapped MFMA + scalar-coalesced
// epilogue. Output: sorted h_ws row rb + m0 + mrow.
__global__ __launch_bounds__(512) void gemm1_k(
    const _Float16* __restrict__ xh, const _Float16* __restrict__ w13t,
    const int* __restrict__ counts, const int* __restrict__ lists,
    _Float16* __restrict__ h_ws) {
  int e, m0, ne, rb;
  if (!tile_decode_g<8>(counts, blockIdx.y, e, m0, ne, rb)) return;
  const int n0 = blockIdx.x * 64;

  __shared__ int rows[256];
  __shared__ __align__(16) _Float16 As[256 * 32];   // 16 KB
  __shared__ __align__(16) _Float16 Bgs[64 * 32];   // 4 KB
  __shared__ __align__(16) _Float16 Bus[64 * 32];   // 4 KB

  const int tid = threadIdx.x;
  if (tid < 256) {
    const int m = m0 + tid;
    rows[tid] = (m < ne) ? lists[e * CAP + m] : -1;
  }
  __syncthreads();

  // staging: row sr = tid/4 (0..127), seg s4 = tid%4 (16B), XOR swizzle on
  // global side. A: rows sr and 128+sr. B: sr<64 loads gate row sr; sr>=64
  // loads up row sr-64.
  const int sr = tid >> 2;
  const int s4 = tid & 3;
  const int segoff = ((s4 ^ ((sr >> 1) & 3)) * 8);
  const int pa0 = rows[sr];
  const int pa1 = rows[128 + sr];
  const int t0 = (pa0 >= 0) ? (pa0 >> 1) : 0;
  const int t1 = (pa1 >= 0) ? (pa1 >> 1) : 0;
  const _Float16* ga0 = xh + (size_t)t0 * H_DIM + segoff;
  const _Float16* ga1 = xh + (size_t)t1 * H_DIM + segoff;
  const int isU = sr >> 6;          // 0: gate rows, 1: up rows
  const int brow = sr & 63;
  const _Float16* gb = w13t +
      ((size_t)e * 2 * I_DIM + (size_t)isU * I_DIM + n0 + brow) * H_DIM + segoff;
  _Float16* la0 = As + sr * 32 + s4 * 8;
  _Float16* la1 = As + (128 + sr) * 32 + s4 * 8;
  _Float16* lb = (isU ? Bus : Bgs) + brow * 32 + s4 * 8;

  const int lane = tid & 63;
  const int wid = tid >> 6;
  const int wm = wid & 3;           // 4 m-groups of 64 rows
  const int wn = wid >> 2;          // 2 n-groups of 32 cols
  const int fm = lane & 15;
  const int q = lane >> 4;
  int aoff[4], boff[2];
  for (int mi = 0; mi < 4; ++mi) {
    const int rA = wm * 64 + mi * 16 + fm;
    aoff[mi] = rA * 32 + ((q ^ ((rA >> 1) & 3)) * 8);
  }
  for (int ni = 0; ni < 2; ++ni) {
    const int cB = wn * 32 + ni * 16 + fm;
    boff[ni] = cB * 32 + ((q ^ ((cB >> 1) & 3)) * 8);
  }

  f32x4 accg[4][2] = {};
  f32x4 accu[4][2] = {};

  for (int k0 = 0; k0 < H_DIM; k0 += 32) {
    glds16(ga0 + k0, la0);
    glds16(ga1 + k0, la1);
    glds16(gb + k0, lb);
    __syncthreads();

    half8 af[4], bg[2], bu[2];
    for (int mi = 0; mi < 4; ++mi) af[mi] = *(const half8*)&As[aoff[mi]];
    for (int ni = 0; ni < 2; ++ni) {
      bg[ni] = *(const half8*)&Bgs[boff[ni]];
      bu[ni] = *(const half8*)&Bus[boff[ni]];
    }
    for (int mi = 0; mi < 4; ++mi)
      for (int ni = 0; ni < 2; ++ni) {
        accg[mi][ni] = __builtin_amdgcn_mfma_f32_16x16x32_f16(af[mi], bg[ni], accg[mi][ni], 0, 0, 0);
        accu[mi][ni] = __builtin_amdgcn_mfma_f32_16x16x32_f16(af[mi], bu[ni], accu[mi][ni], 0, 0, 0);
      }
    __syncthreads();
  }

  // epilogue: C/D layout col=lane&15, row=q*4+reg; silu(g)*u -> sorted h_ws
  for (int mi = 0; mi < 4; ++mi)
    for (int r = 0; r < 4; ++r) {
      const int mrow = wm * 64 + mi * 16 + q * 4 + r;
      if (m0 + mrow >= ne) continue;
      _Float16* hrow = h_ws + (size_t)(rb + m0 + mrow) * I_DIM + n0;
      for (int ni = 0; ni < 2; ++ni) {
        const int c = wn * 32 + ni * 16 + fm;
        const float g = accg[mi][ni][r];
        const float u = accu[mi][ni][r];
        hrow[c] = (_Float16)(g / (1.0f + __expf(-g)) * u);
      }
    }
}

// ------------------------------------------------------------------ GEMM 2 ---
// R28: 256 sequential sorted-h rows x 64 out cols, K=1024, BK=64, 2-phase
// double-buffered (R22 loop), 512 threads / 8 waves (4m x 2n, wave 64x32).
// LDS: A 2x256x64x2B = 64KB + B 2x64x64x2B = 16KB = 80KB -> 2 blocks/CU
// (16 waves). Demand ~200MB (was 408 at M=128). Grid: x = m-tile (fastest,
// 256-gran), y = n0. MFMA SWAPPED: f32x4 epilogue (verified R19/R22).
__global__ __launch_bounds__(512) void gemm2_k(
    const _Float16* __restrict__ h_ws, const _Float16* __restrict__ w2t,
    const int* __restrict__ counts, const int* __restrict__ lists,
    float* __restrict__ out) {
  int e, m0, ne, rb;
  if (!tile_decode_g<8>(counts, blockIdx.x, e, m0, ne, rb)) return;
  const int n0 = blockIdx.y * 64;

  __shared__ int rows[256];
  __shared__ __align__(16) _Float16 As[2][256 * 64];  // 64 KB
  __shared__ __align__(16) _Float16 Bs[2][64 * 64];   // 16 KB

  const int tid = threadIdx.x;
  if (tid < 256) {
    const int m = m0 + tid;
    rows[tid] = (m < ne) ? lists[e * CAP + m] : -1;
  }
  // no barrier needed: rows[] first read in epilogue, loop barriers cover it

  // staging: 8 segs of 16B per 64-k row. r8 = tid/8 (0..63), s8 = tid%8.
  // A: 4 passes of 64 rows; B: one row per thread group (64 rows total).
  const int s8 = tid & 7;
  const int r8 = tid >> 3;  // 0..63
  const int sw = ((s8 ^ (r8 & 7)) * 8);
  const _Float16* gA[4];
  int lA[4];
  for (int pa = 0; pa < 4; ++pa) {
    const int m = pa * 64 + r8;
    int grow = rb + m0 + m;                       // sequential sorted rows
    if (grow > P_PAIRS - 1) grow = P_PAIRS - 1;   // clamp last-tile overrun
    gA[pa] = h_ws + (size_t)grow * I_DIM + sw;
    lA[pa] = m * 64 + s8 * 8;
  }
  const _Float16* gB = w2t + ((size_t)e * H_DIM + n0 + r8) * I_DIM + sw;
  const int lB = r8 * 64 + s8 * 8;

  const int lane = tid & 63;
  const int wid = tid >> 6;
  const int wm = wid & 3;           // 4 m-groups of 64 rows
  const int wn = wid >> 2;          // 2 n-groups of 32 cols
  const int fm = lane & 15;
  const int q = lane >> 4;
  int aoff[2][4], boff[2][2];
  for (int ks = 0; ks < 2; ++ks) {
    for (int mi = 0; mi < 4; ++mi) {
      const int rA = wm * 64 + mi * 16 + fm;
      aoff[ks][mi] = rA * 64 + (((ks * 4 + q) ^ (rA & 7)) * 8);
    }
    for (int ni = 0; ni < 2; ++ni) {
      const int cB = wn * 32 + ni * 16 + fm;
      boff[ks][ni] = cB * 64 + (((ks * 4 + q) ^ (cB & 7)) * 8);
    }
  }

  f32x4 acc[4][2] = {};

#define G2_STAGE(buf, k0)                                  \
  do {                                                     \
    for (int pa = 0; pa < 4; ++pa)                         \
      glds16(gA[pa] + (k0), &As[buf][lA[pa]]);             \
    glds16(gB + (k0), &Bs[buf][lB]);                       \
  } while (0)

#define G2_COMPUTE(buf)                                                          \
  do {                                                                           \
    for (int ks = 0; ks < 2; ++ks) {                                             \
      half8 af[4], bf[2];                                                        \
      for (int mi = 0; mi < 4; ++mi)                                             \
        af[mi] = *(const half8*)&As[buf][aoff[ks][mi]];                          \
      for (int ni = 0; ni < 2; ++ni)                                             \
        bf[ni] = *(const half8*)&Bs[buf][boff[ks][ni]];                          \
      for (int mi = 0; mi < 4; ++mi)                                             \
        for (int ni = 0; ni < 2; ++ni)                                           \
          acc[mi][ni] = __builtin_amdgcn_mfma_f32_16x16x32_f16(                  \
              bf[ni], af[mi], acc[mi][ni], 0, 0, 0);                             \
    }                                                                            \
  } while (0)

  G2_STAGE(0, 0);
  __syncthreads();  // buf0 ready
  for (int k0 = 0; k0 < I_DIM; k0 += 128) {
    G2_STAGE(1, k0 + 64);     // k0+64 <= 960 always valid
    G2_COMPUTE(0);
    __syncthreads();
    if (k0 + 128 < I_DIM) G2_STAGE(0, k0 + 128);
    G2_COMPUTE(1);
    __syncthreads();
  }
#undef G2_STAGE
#undef G2_COMPUTE

  // epilogue (C^T layout): lane fm = out row, regs = 4 consecutive cols
  for (int mi = 0; mi < 4; ++mi) {
    const int p = rows[wm * 64 + mi * 16 + fm];
    if (p < 0) continue;
    float* orow = out + (size_t)p * H_DIM + n0;
    for (int ni = 0; ni < 2; ++ni)
      *(f32x4*)&orow[wn * 32 + ni * 16 + q * 4] = acc[mi][ni];
  }
}

// ------------------------------------------------------------------ launch ---
extern "C" void kernel_launch(void* const* d_in, const int* in_sizes, int n_in,
                              void* d_out, int out_size, void* d_ws, size_t ws_size,
                              hipStream_t stream) {
  const float* x = (const float*)d_in[0];
  const int* idx = (const int*)d_in[1];
  const float* w13 = (const float*)d_in[2];
  const float* w2 = (const float*)d_in[3];

  char* ws = (char*)d_ws;
  int* counts = (int*)ws;                  // 8 ints (pad to 2048)
  int* lists = (int*)(ws + 2048);          // 512 KB
  const size_t OFF_XH = 2048 + (size_t)E_NUM * CAP * 4;
  const size_t OFF_W13T = OFF_XH + (size_t)P_PAIRS / 2 * H_DIM * 2;          // +8.39 MB
  const size_t OFF_W2T = OFF_W13T + (size_t)E_NUM * 2 * I_DIM * H_DIM * 2;   // +16.78 MB
  const size_t OFF_H = OFF_W2T + (size_t)E_NUM * H_DIM * I_DIM * 2;          // +8.39 MB
  _Float16* xh = (_Float16*)(ws + OFF_XH);     // [B*S][H] fp16
  _Float16* w13t = (_Float16*)(ws + OFF_W13T); // [E][2I][H] fp16
  _Float16* w2t = (_Float16*)(ws + OFF_W2T);   // [E][H][I]  fp16
  _Float16* h_ws = (_Float16*)(ws + OFF_H);    // [P][I] fp16, SORTED rows (33.5 MB)

  hipMemsetAsync(d_ws, 0, 128, stream);  // zero expert counts
  prep_k<<<dim3(PREP_BLOCKS), 256, 0, stream>>>(x, idx, w13, w2, counts, lists,
                                                xh, w13t, w2t);
  gemm1_k<<<dim3(I_DIM / 64, MAX_TILES1), 512, 0, stream>>>(
      xh, w13t, counts, lists, h_ws);
  gemm2_k<<<dim3(MAX_TILES1, H_DIM / 64), 512, 0, stream>>>(
      h_ws, w2t, counts, lists, (float*)d_out);
}

// Round 20
// 200.493 us; speedup vs baseline: 1.1541x; 1.1541x over previous
//
#include <hip/hip_runtime.h>

// MoE top-2 SwiGLU (fp32 in/out, fp16 MFMA internal).
// Dispatches: memset(counts) -> prep_k (route + cvt x + transpose w13 + w2) ->
// gemm1 (256x(64g+64u), BK=32, 512thr/8wave) ->
// gemm2 (128x64, BK=64, dbuf).
// R30 = revert R28 (gemm2 M=256 FAILED decisively: 69.7us vs 41.9, FETCH
// 66.6->166MB, LDS 82944 -> 1 block/CU [my 2-blk arithmetic was wrong],
// MfmaUtil 9.4 — M=256 pattern loses inter-block L2/L3 reuse after the
// harness's 268MB fill flushes L3 each iter; became HBM-bound on MORE
// traffic). Demand lever on gemm2 is EXHAUSTED: BK 32/64, N 64/128,
// M 128/256, sbuf/dbuf all tried; R22 config (41.9us direct counters) is
// the family optimum.
// Consolidated best config (= R27, residual 141.9 slow-machine):
//   gemm1 M=256 (same-machine win x5: 62.5-63.3 slow vs 65.9 M=128);
//   gemm2 = R22-measured 128x64 BK=64 dbuf;
//   prep = R10 transpose.
// Plateau decomposition (direct measurements): fill 41.5 (harness re-poison,
// untouchable) + gemm1 ~58-60 + gemm2 ~42 + prep <41 + gaps ~9.
// Regression ledger: gemm1 dbuf (R11), BK=64, swap epilogue (R19), absorption
// (R18/R21), split dispatch (R22), gemm2 M=256 (R28). Wins: gemm1 M=256
// (R26), gemm2 dbuf (R11), sorted h_ws + deferred scatter, XOR seg swizzle
// (conflicts 0 everywhere). Machine noise: HBM rate varies -8% across runs;
// derived OccupancyPercent unreliable.
// Session bests: R20 196.6 (fast node).

#define H_DIM 512
#define I_DIM 1024
#define E_NUM 8
#define P_PAIRS 16384
#define CAP P_PAIRS
#define MAX_TILES 136    // 128-granularity: sum ceil(ne/128) <= 135
#define MAX_TILES1 71    // 256-granularity: sum ceil(ne/256) <= 64+7

// prep_k block ranges
#define PREP_TW13 2048              // (2I/64=32) x (H/64=8) x E=8
#define PREP_TW2 1024               // (H/64=8) x (I/64=16) x E=8
#define PREP_CVT 2048               // 8192*512 / (256*8)
#define PREP_ROUTE 64               // 16384 / 256
#define PREP_BLOCKS (PREP_TW13 + PREP_TW2 + PREP_CVT + PREP_ROUTE)

typedef _Float16 half8 __attribute__((ext_vector_type(8)));
typedef float f32x4 __attribute__((ext_vector_type(4)));
typedef unsigned int u32;
typedef const __attribute__((address_space(1))) u32* gas_t;
typedef __attribute__((address_space(3))) u32* las_t;

__device__ __forceinline__ void glds16(const void* g, void* l) {
  __builtin_amdgcn_global_load_lds((gas_t)g, (las_t)l, 16, 0, 0);
}

// derive (e, m0, ne, rowbase) for compact tile id ty at GRAN granularity
template <int GRAN_LOG2>
__device__ __forceinline__ bool tile_decode_g(const int* counts, int ty, int& e,
                                              int& m0, int& ne, int& rb) {
  int base = 0;
  rb = 0;
  const int gm1 = (1 << GRAN_LOG2) - 1;
  for (e = 0; e < E_NUM; ++e) {
    ne = counts[e];
    const int nt = (ne + gm1) >> GRAN_LOG2;
    if (ty < base + nt) { m0 = (ty - base) << GRAN_LOG2; return true; }
    base += nt;
    rb += ne;
  }
  return false;
}

// ------------------------------------------------------------------- prep ---
__global__ __launch_bounds__(256) void prep_k(
    const float* __restrict__ x, const int* __restrict__ idx,
    const float* __restrict__ w13, const float* __restrict__ w2,
    int* __restrict__ counts, int* __restrict__ lists,
    _Float16* __restrict__ xh, _Float16* __restrict__ w13t,
    _Float16* __restrict__ w2t) {
  __shared__ __align__(16) _Float16 tile[64][72];  // 9216 B (route reuses head)
  const int b = blockIdx.x;
  const int tid = threadIdx.x;

  if (b < PREP_TW13 + PREP_TW2) {
    const float* src;
    _Float16* dst;
    int R, C, c0, r0;
    if (b < PREP_TW13) {
      R = H_DIM; C = 2 * I_DIM;
      const int e = b >> 8;
      c0 = (b & 31) * 64;
      r0 = ((b >> 5) & 7) * 64;
      src = w13 + (size_t)e * R * C;
      dst = w13t + (size_t)e * C * R;
    } else {
      const int l = b - PREP_TW13;
      R = I_DIM; C = H_DIM;
      const int e = l >> 7;
      c0 = (l & 7) * 64;
      r0 = ((l >> 3) & 15) * 64;
      src = w2 + (size_t)e * R * C;
      dst = w2t + (size_t)e * C * R;
    }
    {
      const int r = tid >> 4;
      const int c4 = (tid & 15) * 4;
      for (int pass = 0; pass < 4; ++pass) {
        f32x4 v = *(const f32x4*)(src + (size_t)(r0 + pass * 16 + r) * C + c0 + c4);
        for (int j = 0; j < 4; ++j) tile[c4 + j][pass * 16 + r] = (_Float16)v[j];
      }
    }
    __syncthreads();
    {
      const int c = tid >> 3;
      const int r8 = (tid & 7) * 8;
      for (int pass = 0; pass < 2; ++pass) {
        half8 h = *(const half8*)&tile[pass * 32 + c][r8];
        *(half8*)(dst + (size_t)(c0 + pass * 32 + c) * R + r0 + r8) = h;
      }
    }
  } else if (b < PREP_TW13 + PREP_TW2 + PREP_CVT) {
    const int l = b - (PREP_TW13 + PREP_TW2);
    const size_t i = ((size_t)l * 256 + tid) * 8;
    f32x4 v0 = *(const f32x4*)(x + i);
    f32x4 v1 = *(const f32x4*)(x + i + 4);
    half8 h;
    for (int j = 0; j < 4; ++j) { h[j] = (_Float16)v0[j]; h[j + 4] = (_Float16)v1[j]; }
    *(half8*)(xh + i) = h;
  } else {
    int* lcnt = (int*)&tile[0][0];
    int* lbase = lcnt + E_NUM;
    const int l = b - (PREP_TW13 + PREP_TW2 + PREP_CVT);
    if (tid < E_NUM) lcnt[tid] = 0;
    __syncthreads();
    const int p = l * 256 + tid;
    const int e = idx[p];
    const int r = atomicAdd(&lcnt[e], 1);
    __syncthreads();
    if (tid < E_NUM) lbase[tid] = atomicAdd(&counts[tid], lcnt[tid]);
    __syncthreads();
    lists[e * CAP + lbase[e] + r] = p;
  }
}

// ------------------------------------------------------------------ GEMM 1 ---
// R26: 256 gathered pairs x (64 gate + 64 up cols), K=512, BK=32.
// 512 threads, 8 waves (4m x 2n); per-wave tile 64x32x(g+u) = proven shape.
// Grid: x = n0 (fastest, shares random A-gather), y = m-tile (256-gran).
// Single-buffered 2-barrier loop; non-swapped MFMA + scalar-coalesced
// epilogue. Output: sorted h_ws row rb + m0 + mrow.
__global__ __launch_bounds__(512) void gemm1_k(
    const _Float16* __restrict__ xh, const _Float16* __restrict__ w13t,
    const int* __restrict__ counts, const int* __restrict__ lists,
    _Float16* __restrict__ h_ws) {
  int e, m0, ne, rb;
  if (!tile_decode_g<8>(counts, blockIdx.y, e, m0, ne, rb)) return;
  const int n0 = blockIdx.x * 64;

  __shared__ int rows[256];
  __shared__ __align__(16) _Float16 As[256 * 32];   // 16 KB
  __shared__ __align__(16) _Float16 Bgs[64 * 32];   // 4 KB
  __shared__ __align__(16) _Float16 Bus[64 * 32];   // 4 KB

  const int tid = threadIdx.x;
  if (tid < 256) {
    const int m = m0 + tid;
    rows[tid] = (m < ne) ? lists[e * CAP + m] : -1;
  }
  __syncthreads();

  // staging: row sr = tid/4 (0..127), seg s4 = tid%4 (16B), XOR swizzle on
  // global side. A: rows sr and 128+sr. B: sr<64 loads gate row sr; sr>=64
  // loads up row sr-64.
  const int sr = tid >> 2;
  const int s4 = tid & 3;
  const int segoff = ((s4 ^ ((sr >> 1) & 3)) * 8);
  const int pa0 = rows[sr];
  const int pa1 = rows[128 + sr];
  const int t0 = (pa0 >= 0) ? (pa0 >> 1) : 0;
  const int t1 = (pa1 >= 0) ? (pa1 >> 1) : 0;
  const _Float16* ga0 = xh + (size_t)t0 * H_DIM + segoff;
  const _Float16* ga1 = xh + (size_t)t1 * H_DIM + segoff;
  const int isU = sr >> 6;          // 0: gate rows, 1: up rows
  const int brow = sr & 63;
  const _Float16* gb = w13t +
      ((size_t)e * 2 * I_DIM + (size_t)isU * I_DIM + n0 + brow) * H_DIM + segoff;
  _Float16* la0 = As + sr * 32 + s4 * 8;
  _Float16* la1 = As + (128 + sr) * 32 + s4 * 8;
  _Float16* lb = (isU ? Bus : Bgs) + brow * 32 + s4 * 8;

  const int lane = tid & 63;
  const int wid = tid >> 6;
  const int wm = wid & 3;           // 4 m-groups of 64 rows
  const int wn = wid >> 2;          // 2 n-groups of 32 cols
  const int fm = lane & 15;
  const int q = lane >> 4;
  int aoff[4], boff[2];
  for (int mi = 0; mi < 4; ++mi) {
    const int rA = wm * 64 + mi * 16 + fm;
    aoff[mi] = rA * 32 + ((q ^ ((rA >> 1) & 3)) * 8);
  }
  for (int ni = 0; ni < 2; ++ni) {
    const int cB = wn * 32 + ni * 16 + fm;
    boff[ni] = cB * 32 + ((q ^ ((cB >> 1) & 3)) * 8);
  }

  f32x4 accg[4][2] = {};
  f32x4 accu[4][2] = {};

  for (int k0 = 0; k0 < H_DIM; k0 += 32) {
    glds16(ga0 + k0, la0);
    glds16(ga1 + k0, la1);
    glds16(gb + k0, lb);
    __syncthreads();

    half8 af[4], bg[2], bu[2];
    for (int mi = 0; mi < 4; ++mi) af[mi] = *(const half8*)&As[aoff[mi]];
    for (int ni = 0; ni < 2; ++ni) {
      bg[ni] = *(const half8*)&Bgs[boff[ni]];
      bu[ni] = *(const half8*)&Bus[boff[ni]];
    }
    for (int mi = 0; mi < 4; ++mi)
      for (int ni = 0; ni < 2; ++ni) {
        accg[mi][ni] = __builtin_amdgcn_mfma_f32_16x16x32_f16(af[mi], bg[ni], accg[mi][ni], 0, 0, 0);
        accu[mi][ni] = __builtin_amdgcn_mfma_f32_16x16x32_f16(af[mi], bu[ni], accu[mi][ni], 0, 0, 0);
      }
    __syncthreads();
  }

  // epilogue: C/D layout col=lane&15, row=q*4+reg; silu(g)*u -> sorted h_ws
  for (int mi = 0; mi < 4; ++mi)
    for (int r = 0; r < 4; ++r) {
      const int mrow = wm * 64 + mi * 16 + q * 4 + r;
      if (m0 + mrow >= ne) continue;
      _Float16* hrow = h_ws + (size_t)(rb + m0 + mrow) * I_DIM + n0;
      for (int ni = 0; ni < 2; ++ni) {
        const int c = wn * 32 + ni * 16 + fm;
        const float g = accg[mi][ni][r];
        const float u = accu[mi][ni][r];
        hrow[c] = (_Float16)(g / (1.0f + __expf(-g)) * u);
      }
    }
}

// ------------------------------------------------------------------ GEMM 2 ---
// R22-measured config (41.9us direct counters): 128 sequential sorted-h rows
// x 64 out cols, K=1024, BK=64, 2-phase double-buffered, one barrier/step.
// Grid: x = m-tile (fastest), y = n0 [R9 evidence].
// MFMA operands SWAPPED: vectorized f32x4 epilogue (verified R19).
__global__ __launch_bounds__(256) void gemm2_k(
    const _Float16* __restrict__ h_ws, const _Float16* __restrict__ w2t,
    const int* __restrict__ counts, const int* __restrict__ lists,
    float* __restrict__ out) {
  int e, m0, ne, rb;
  if (!tile_decode_g<7>(counts, blockIdx.x, e, m0, ne, rb)) return;
  const int n0 = blockIdx.y * 64;

  __shared__ int rows[128];
  __shared__ __align__(16) _Float16 As[2][128 * 64];  // 32 KB
  __shared__ __align__(16) _Float16 Bs[2][64 * 64];   // 16 KB

  const int tid = threadIdx.x;
  if (tid < 128) {
    const int m = m0 + tid;
    rows[tid] = (m < ne) ? lists[e * CAP + m] : -1;
  }
  // no barrier needed: rows[] first read in epilogue, loop barriers cover it

  const int s8 = tid & 7;
  const int sr8 = tid >> 3;  // 0..31
  const int sw = ((s8 ^ (sr8 & 7)) * 8);
  const _Float16* gA[4];
  int lA[4];
  for (int pa = 0; pa < 4; ++pa) {
    const int m = pa * 32 + sr8;
    int grow = rb + m0 + m;                       // sequential sorted rows
    if (grow > P_PAIRS - 1) grow = P_PAIRS - 1;   // clamp last-tile overrun
    gA[pa] = h_ws + (size_t)grow * I_DIM + sw;
    lA[pa] = m * 64 + s8 * 8;
  }
  const _Float16* gB[2];
  int lB[2];
  for (int pb = 0; pb < 2; ++pb) {
    const int n = pb * 32 + sr8;
    gB[pb] = w2t + ((size_t)e * H_DIM + n0 + n) * I_DIM + sw;
    lB[pb] = n * 64 + s8 * 8;
  }

  const int lane = tid & 63;
  const int wid = tid >> 6;
  const int wm = wid & 1;
  const int wn = wid >> 1;
  const int fm = lane & 15;
  const int q = lane >> 4;
  int aoff[2][4], boff[2][2];
  for (int ks = 0; ks < 2; ++ks) {
    for (int mi = 0; mi < 4; ++mi) {
      const int rA = wm * 64 + mi * 16 + fm;
      aoff[ks][mi] = rA * 64 + (((ks * 4 + q) ^ (rA & 7)) * 8);
    }
    for (int ni = 0; ni < 2; ++ni) {
      const int cB = wn * 32 + ni * 16 + fm;
      boff[ks][ni] = cB * 64 + (((ks * 4 + q) ^ (cB & 7)) * 8);
    }
  }

  f32x4 acc[4][2] = {};

#define G2_STAGE(buf, k0)                                  \
  do {                                                     \
    for (int pa = 0; pa < 4; ++pa)                         \
      glds16(gA[pa] + (k0), &As[buf][lA[pa]]);             \
    for (int pb = 0; pb < 2; ++pb)                         \
      glds16(gB[pb] + (k0), &Bs[buf][lB[pb]]);             \
  } while (0)

#define G2_COMPUTE(buf)                                                          \
  do {                                                                           \
    for (int ks = 0; ks < 2; ++ks) {                                             \
      half8 af[4], bf[2];                                                        \
      for (int mi = 0; mi < 4; ++mi)                                             \
        af[mi] = *(const half8*)&As[buf][aoff[ks][mi]];                          \
      for (int ni = 0; ni < 2; ++ni)                                             \
        bf[ni] = *(const half8*)&Bs[buf][boff[ks][ni]];                          \
      for (int mi = 0; mi < 4; ++mi)                                             \
        for (int ni = 0; ni < 2; ++ni)                                           \
          acc[mi][ni] = __builtin_amdgcn_mfma_f32_16x16x32_f16(                  \
              bf[ni], af[mi], acc[mi][ni], 0, 0, 0);                             \
    }                                                                            \
  } while (0)

  G2_STAGE(0, 0);
  __syncthreads();  // buf0 ready
  for (int k0 = 0; k0 < I_DIM; k0 += 128) {
    G2_STAGE(1, k0 + 64);     // k0+64 <= 960 always valid
    G2_COMPUTE(0);
    __syncthreads();
    if (k0 + 128 < I_DIM) G2_STAGE(0, k0 + 128);
    G2_COMPUTE(1);
    __syncthreads();
  }
#undef G2_STAGE
#undef G2_COMPUTE

  // epilogue (C^T layout): lane fm = out row, regs = 4 consecutive cols
  for (int mi = 0; mi < 4; ++mi) {
    const int p = rows[wm * 64 + mi * 16 + fm];
    if (p < 0) continue;
    float* orow = out + (size_t)p * H_DIM + n0;
    for (int ni = 0; ni < 2; ++ni)
      *(f32x4*)&orow[wn * 32 + ni * 16 + q * 4] = acc[mi][ni];
  }
}

// ------------------------------------------------------------------ launch ---
extern "C" void kernel_launch(void* const* d_in, const int* in_sizes, int n_in,
                              void* d_out, int out_size, void* d_ws, size_t ws_size,
                              hipStream_t stream) {
  const float* x = (const float*)d_in[0];
  const int* idx = (const int*)d_in[1];
  const float* w13 = (const float*)d_in[2];
  const float* w2 = (const float*)d_in[3];

  char* ws = (char*)d_ws;
  int* counts = (int*)ws;                  // 8 ints (pad to 2048)
  int* lists = (int*)(ws + 2048);          // 512 KB
  const size_t OFF_XH = 2048 + (size_t)E_NUM * CAP * 4;
  const size_t OFF_W13T = OFF_XH + (size_t)P_PAIRS / 2 * H_DIM * 2;          // +8.39 MB
  const size_t OFF_W2T = OFF_W13T + (size_t)E_NUM * 2 * I_DIM * H_DIM * 2;   // +16.78 MB
  const size_t OFF_H = OFF_W2T + (size_t)E_NUM * H_DIM * I_DIM * 2;          // +8.39 MB
  _Float16* xh = (_Float16*)(ws + OFF_XH);     // [B*S][H] fp16
  _Float16* w13t = (_Float16*)(ws + OFF_W13T); // [E][2I][H] fp16
  _Float16* w2t = (_Float16*)(ws + OFF_W2T);   // [E][H][I]  fp16
  _Float16* h_ws = (_Float16*)(ws + OFF_H);    // [P][I] fp16, SORTED rows (33.5 MB)

  hipMemsetAsync(d_ws, 0, 128, stream);  // zero expert counts
  prep_k<<<dim3(PREP_BLOCKS), 256, 0, stream>>>(x, idx, w13, w2, counts, lists,
                                                xh, w13t, w2t);
  gemm1_k<<<dim3(I_DIM / 64, MAX_TILES1), 512, 0, stream>>>(
      xh, w13t, counts, lists, h_ws);
  gemm2_k<<<dim3(MAX_TILES, H_DIM / 64), 256, 0, stream>>>(
      h_ws, w2t, counts, lists, (float*)d_out);
}